// Round 6
// baseline (70.993 us; speedup 1.0000x reference)
//
#include <hip/hip_runtime.h>
#include <cmath>

// PCEN: out = (x / (FLOOR + ema(x,w))^a + d)^(1/r) - d^(1/r), plus x_length passthrough.
// One WAVE per (b,c) row of T=8000 (4 rows per 256-thread block, fully independent:
// no LDS, no barriers). Row processed as 32 tiles of 256 elems; each lane owns one
// float4 per tile (per-lane-contiguous == coalesced). EMA recurrence: constant-
// multiplier Kogge-Stone scan (6 shfl + 6 fma), carry broadcast via shfl(b,63).
// Pointwise math: raw v_log_f32/v_exp_f32; root==2 fast path via v_sqrt_f32.

constexpr int T_LEN = 8000;
constexpr int T4    = T_LEN / 4;             // 2000 float4 per row
constexpr int BLK   = 256;
constexpr int NT    = (T4 + 63) / 64;        // 32 tiles (last: 16 lanes active)

__device__ __forceinline__ float fexp2(float x) { return __builtin_amdgcn_exp2f(x); }
__device__ __forceinline__ float flog2(float x) { return __builtin_amdgcn_logf(x); }
__device__ __forceinline__ float fsqrt(float x) { return __builtin_amdgcn_sqrtf(x); }

__global__ __launch_bounds__(BLK, 8) void pcen_kernel(
    const float* __restrict__ x, const float* __restrict__ alpha,
    const float* __restrict__ delta, const float* __restrict__ root,
    const float* __restrict__ ema_w, const int* __restrict__ xlen,
    float* __restrict__ out, int C, int rows, int nlen)
{
    const int tid  = threadIdx.x;
    const int lane = tid & 63;
    const int wid  = tid >> 6;
    const int row  = blockIdx.x * 4 + wid;

    if (row < rows) {
        const int c = row % C;

        const float w     = fminf(fmaxf(ema_w[c], 0.0f), 1.0f);
        const float p     = 1.0f - w;            // EMA decay
        const float na    = -fminf(alpha[c], 1.0f);
        const float r     = fmaxf(root[c], 1.0f);
        const float inv_r = 1.0f / r;
        const float d     = delta[c];
        const bool  use_sqrt = (r == 2.0f);
        const float droot = use_sqrt ? fsqrt(d) : fexp2(inv_r * flog2(d));

        // scan constants by repeated squaring
        const float c1 = p * p * p * p;                       // p^4 (segment decay)
        const float c2 = c1 * c1, c3 = c2 * c2, c4 = c3 * c3,
                    c5 = c4 * c4, c6 = c5 * c5;               // p^8 .. p^128
        const float q  = c6 * c6;                             // p^256 (tile decay)
        // p^(4*lane); lane==0 select avoids 0*(-inf)=NaN when p==0
        const float lp  = flog2(p);
        const float p4l = (lane == 0) ? 1.0f : fexp2(4.0f * (float)lane * lp);

        const float4* x4 = reinterpret_cast<const float4*>(x + (size_t)row * T_LEN);
        float4*       o4 = reinterpret_cast<float4*>(out + (size_t)row * T_LEN);

        float4 v = x4[lane];                       // tile 0 (64 < 2000: always valid)
        float carry = __shfl(v.x, 0, 64);          // jax scan init: acc = x[...,0]

        for (int t = 0; t < NT; ++t) {
            const int  j      = t * 64 + lane;
            const bool active = (j < T4);

            // prefetch next tile (issued before the dependent scan chain)
            const int jn = j + 64;
            float4 vn = make_float4(0.f, 0.f, 0.f, 0.f);
            if (jn < T4) vn = x4[jn];

            // ---- pass 1: per-lane transform  B = w * Horner over own 4 elems ----
            float s = v.x;
            s = fmaf(s, p, v.y); s = fmaf(s, p, v.z); s = fmaf(s, p, v.w);
            float b = active ? (w * s) : 0.0f;

            // ---- Kogge-Stone inclusive scan, constant multipliers ----
            float pb;
            pb = __shfl_up(b,  1, 64); if (lane >=  1) b = fmaf(c1, pb, b);
            pb = __shfl_up(b,  2, 64); if (lane >=  2) b = fmaf(c2, pb, b);
            pb = __shfl_up(b,  4, 64); if (lane >=  4) b = fmaf(c3, pb, b);
            pb = __shfl_up(b,  8, 64); if (lane >=  8) b = fmaf(c4, pb, b);
            pb = __shfl_up(b, 16, 64); if (lane >= 16) b = fmaf(c5, pb, b);
            pb = __shfl_up(b, 32, 64); if (lane >= 32) b = fmaf(c6, pb, b);

            float eb = __shfl_up(b, 1, 64);          // exclusive prefix
            if (lane == 0) eb = 0.0f;
            const float tb = __shfl(b, 63, 64);      // tile total (broadcast)

            float acc = fmaf(p4l, carry, eb);        // acc entering this lane's 4 elems
            carry = fmaf(q, carry, tb);              // next-tile carry

            // ---- pass 2: exact EMA replay + pointwise PCEN, coalesced store ----
            if (active) {
                float4 u = v, o;
                if (use_sqrt) {
                    acc = fmaf(w, u.x, p * acc);
                    o.x = fsqrt(fmaf(u.x, fexp2(na * flog2(acc + 1e-12f)), d)) - droot;
                    acc = fmaf(w, u.y, p * acc);
                    o.y = fsqrt(fmaf(u.y, fexp2(na * flog2(acc + 1e-12f)), d)) - droot;
                    acc = fmaf(w, u.z, p * acc);
                    o.z = fsqrt(fmaf(u.z, fexp2(na * flog2(acc + 1e-12f)), d)) - droot;
                    acc = fmaf(w, u.w, p * acc);
                    o.w = fsqrt(fmaf(u.w, fexp2(na * flog2(acc + 1e-12f)), d)) - droot;
                } else {
                    acc = fmaf(w, u.x, p * acc);
                    o.x = fexp2(inv_r * flog2(fmaf(u.x, fexp2(na * flog2(acc + 1e-12f)), d))) - droot;
                    acc = fmaf(w, u.y, p * acc);
                    o.y = fexp2(inv_r * flog2(fmaf(u.y, fexp2(na * flog2(acc + 1e-12f)), d))) - droot;
                    acc = fmaf(w, u.z, p * acc);
                    o.z = fexp2(inv_r * flog2(fmaf(u.z, fexp2(na * flog2(acc + 1e-12f)), d))) - droot;
                    acc = fmaf(w, u.w, p * acc);
                    o.w = fexp2(inv_r * flog2(fmaf(u.w, fexp2(na * flog2(acc + 1e-12f)), d))) - droot;
                }
                o4[j] = o;
            }
            v = vn;
        }
    }

    // output 1: x_length as float (harness reads whole d_out as f32)
    if (blockIdx.x == 0 && wid == 0) {
        for (int i = lane; i < nlen; i += 64)
            out[(size_t)rows * T_LEN + i] = (float)xlen[i];
    }
}

extern "C" void kernel_launch(void* const* d_in, const int* in_sizes, int n_in,
                              void* d_out, int out_size, void* d_ws, size_t ws_size,
                              hipStream_t stream) {
    const float* x     = (const float*)d_in[0];
    const float* alpha = (const float*)d_in[1];
    const float* delta = (const float*)d_in[2];
    const float* root  = (const float*)d_in[3];
    const float* emaw  = (const float*)d_in[4];
    const int*   xlen  = (const int*)d_in[5];
    float*       out   = (float*)d_out;

    const int C    = in_sizes[1];
    const int rows = in_sizes[0] / T_LEN;  // B*C
    const int nlen = in_sizes[5];

    const int nblk = (rows + 3) / 4;       // 4 rows (waves) per block
    hipLaunchKernelGGL(pcen_kernel, dim3(nblk), dim3(BLK), 0, stream,
                       x, alpha, delta, root, emaw, xlen, out, C, rows, nlen);
}

// Round 7
// 64.715 us; speedup vs baseline: 1.0970x; 1.0970x over previous
//
#include <hip/hip_runtime.h>
#include <cmath>

// PCEN: out = (x / (FLOOR + ema(x,w))^a + d)^(1/r) - d^(1/r), plus x_length passthrough.
// One 256-thread block per (b,c) row of T=8000, processed as 4 tiles of 2048 elems.
// Each thread owns TWO dense float4s per tile (lo at tid, hi at tid+BLK) -> every
// load/store instruction is perfectly coalesced, 2 loads in flight per thread,
// 8 independent transcendental chains per thread in pass 2.
// EMA recurrence: per-segment affine transform + constant-multiplier Kogge-Stone
// wave scan (lo & hi interleaved), ONE LDS/barrier round per tile resolves both
// (hi prefix composes through the block-wide lo total). Parity double-buffered.
// Pointwise math: raw v_log_f32/v_exp_f32; root==2 fast path via v_sqrt_f32.

constexpr int T_LEN = 8000;
constexpr int T4    = T_LEN / 4;                   // 2000 float4 per row
constexpr int BLK   = 256;
constexpr int TILE4 = BLK * 2;                     // 512 float4 per tile
constexpr int NTILE = (T4 + TILE4 - 1) / TILE4;    // 4 tiles (last: hi partially active)

__device__ __forceinline__ float fexp2(float x) { return __builtin_amdgcn_exp2f(x); }
__device__ __forceinline__ float flog2(float x) { return __builtin_amdgcn_logf(x); }
__device__ __forceinline__ float fsqrt(float x) { return __builtin_amdgcn_sqrtf(x); }

__global__ __launch_bounds__(BLK, 6) void pcen_kernel(
    const float* __restrict__ x, const float* __restrict__ alpha,
    const float* __restrict__ delta, const float* __restrict__ root,
    const float* __restrict__ ema_w, const int* __restrict__ xlen,
    float* __restrict__ out, int C, int rows, int nlen)
{
    __shared__ float wLo[2][4], wHi[2][4];   // per-tile wave aggregates, parity dbuf

    const int tid  = threadIdx.x;
    const int lane = tid & 63;
    const int wid  = tid >> 6;
    const int row  = blockIdx.x;
    const int c    = row % C;

    const float w     = fminf(fmaxf(ema_w[c], 0.0f), 1.0f);
    const float p     = 1.0f - w;                 // EMA decay
    const float na    = -fminf(alpha[c], 1.0f);
    const float r     = fmaxf(root[c], 1.0f);
    const float inv_r = 1.0f / r;
    const float d     = delta[c];
    const bool  use_sqrt = (r == 2.0f);
    const float droot = use_sqrt ? fsqrt(d) : fexp2(inv_r * flog2(d));

    // scan constants by repeated squaring
    const float c1 = p * p * p * p;                           // p^4 (segment decay)
    const float c2 = c1 * c1, c3 = c2 * c2, c4 = c3 * c3,
                c5 = c4 * c4, c6 = c5 * c5;                   // p^8 .. p^128
    const float q  = c6 * c6;                                 // p^256 (wave span)
    const float q2 = q * q, q3 = q2 * q;                      // p^512, p^768
    const float ql = q2 * q2;                                 // p^1024 (half-tile span)
    // p^(4*lane); lane==0 select avoids 0*(-inf)=NaN when p==0
    const float lp  = flog2(p);
    const float p4l = (lane == 0) ? 1.0f : fexp2(4.0f * (float)lane * lp);
    const float qw  = (wid == 0) ? 1.0f : (wid == 1) ? q : (wid == 2) ? q2 : q3;

    const float4* x4 = reinterpret_cast<const float4*>(x + (size_t)row * T_LEN);
    float4*       o4 = reinterpret_cast<float4*>(out + (size_t)row * T_LEN);

    float carry = x[(size_t)row * T_LEN];          // jax scan init: acc = x[...,0]

    // tile 0 loads (lo always valid; hi valid for all full tiles)
    float4 v0 = x4[tid];
    float4 v1 = x4[tid + BLK];

    for (int t = 0; t < NTILE; ++t) {
        const int  j0     = t * TILE4 + tid;       // lo float4 index (always < T4)
        const int  j1     = j0 + BLK;              // hi float4 index
        const bool hi_act = (j1 < T4);
        const int  par    = t & 1;

        // ---- prefetch next tile (issued before the dependent scan chain) ----
        float4 n0 = make_float4(0.f, 0.f, 0.f, 0.f);
        float4 n1 = make_float4(0.f, 0.f, 0.f, 0.f);
        const int k0 = j0 + TILE4, k1 = j1 + TILE4;
        if (t + 1 < NTILE) {
            n0 = x4[k0];                           // lo of next tile always valid
            if (k1 < T4) n1 = x4[k1];
        }

        // ---- pass 1: per-segment transforms B = w * Horner over 4 elems ----
        float sl = v0.x;
        sl = fmaf(sl, p, v0.y); sl = fmaf(sl, p, v0.z); sl = fmaf(sl, p, v0.w);
        float bl = w * sl;
        float sh = v1.x;
        sh = fmaf(sh, p, v1.y); sh = fmaf(sh, p, v1.z); sh = fmaf(sh, p, v1.w);
        float bh = hi_act ? (w * sh) : 0.0f;

        // ---- Kogge-Stone inclusive scans (lo & hi interleaved), const mults ----
        float pl, ph;
        pl = __shfl_up(bl,  1, 64); ph = __shfl_up(bh,  1, 64);
        if (lane >=  1) { bl = fmaf(c1, pl, bl); bh = fmaf(c1, ph, bh); }
        pl = __shfl_up(bl,  2, 64); ph = __shfl_up(bh,  2, 64);
        if (lane >=  2) { bl = fmaf(c2, pl, bl); bh = fmaf(c2, ph, bh); }
        pl = __shfl_up(bl,  4, 64); ph = __shfl_up(bh,  4, 64);
        if (lane >=  4) { bl = fmaf(c3, pl, bl); bh = fmaf(c3, ph, bh); }
        pl = __shfl_up(bl,  8, 64); ph = __shfl_up(bh,  8, 64);
        if (lane >=  8) { bl = fmaf(c4, pl, bl); bh = fmaf(c4, ph, bh); }
        pl = __shfl_up(bl, 16, 64); ph = __shfl_up(bh, 16, 64);
        if (lane >= 16) { bl = fmaf(c5, pl, bl); bh = fmaf(c5, ph, bh); }
        pl = __shfl_up(bl, 32, 64); ph = __shfl_up(bh, 32, 64);
        if (lane >= 32) { bl = fmaf(c6, pl, bl); bh = fmaf(c6, ph, bh); }

        if (lane == 63) { wLo[par][wid] = bl; wHi[par][wid] = bh; }
        float ebl = __shfl_up(bl, 1, 64);
        float ebh = __shfl_up(bh, 1, 64);
        if (lane == 0) { ebl = 0.0f; ebh = 0.0f; }
        __syncthreads();

        // ---- compose wave prefixes + inter-tile carry (uniform per wave) ----
        const float L0 = wLo[par][0], L1 = wLo[par][1], L2 = wLo[par][2], L3 = wLo[par][3];
        const float H0 = wHi[par][0], H1 = wHi[par][1], H2 = wHi[par][2], H3 = wHi[par][3];
        float PL = 0.0f, PH = 0.0f;
        if (wid == 1)      { PL = L0;                        PH = H0; }
        else if (wid == 2) { PL = fmaf(q, L0, L1);           PH = fmaf(q, H0, H1); }
        else if (wid == 3) { PL = fmaf(q, fmaf(q, L0, L1), L2);
                             PH = fmaf(q, fmaf(q, H0, H1), H2); }
        const float TloB = fmaf(q, fmaf(q, fmaf(q, L0, L1), L2), L3);
        const float ThiB = fmaf(q, fmaf(q, fmaf(q, H0, H1), H2), H3);

        const float Elo = fmaf(qw, carry, PL);     // value entering this wave's lo span
        const float mid = fmaf(ql, carry, TloB);   // value after all lo (elem 1023)
        const float Ehi = fmaf(qw, mid, PH);       // value entering this wave's hi span
        carry = fmaf(ql, mid, ThiB);               // value after full tile

        float accl = fmaf(p4l, Elo, ebl);          // acc entering lane's lo segment
        float acch = fmaf(p4l, Ehi, ebh);          // acc entering lane's hi segment

        // ---- pass 2: exact EMA replay + pointwise PCEN, coalesced stores ----
        {
            float4 u = v0, o;
            if (use_sqrt) {
                accl = fmaf(w, u.x, p * accl);
                o.x = fsqrt(fmaf(u.x, fexp2(na * flog2(accl + 1e-12f)), d)) - droot;
                accl = fmaf(w, u.y, p * accl);
                o.y = fsqrt(fmaf(u.y, fexp2(na * flog2(accl + 1e-12f)), d)) - droot;
                accl = fmaf(w, u.z, p * accl);
                o.z = fsqrt(fmaf(u.z, fexp2(na * flog2(accl + 1e-12f)), d)) - droot;
                accl = fmaf(w, u.w, p * accl);
                o.w = fsqrt(fmaf(u.w, fexp2(na * flog2(accl + 1e-12f)), d)) - droot;
            } else {
                accl = fmaf(w, u.x, p * accl);
                o.x = fexp2(inv_r * flog2(fmaf(u.x, fexp2(na * flog2(accl + 1e-12f)), d))) - droot;
                accl = fmaf(w, u.y, p * accl);
                o.y = fexp2(inv_r * flog2(fmaf(u.y, fexp2(na * flog2(accl + 1e-12f)), d))) - droot;
                accl = fmaf(w, u.z, p * accl);
                o.z = fexp2(inv_r * flog2(fmaf(u.z, fexp2(na * flog2(accl + 1e-12f)), d))) - droot;
                accl = fmaf(w, u.w, p * accl);
                o.w = fexp2(inv_r * flog2(fmaf(u.w, fexp2(na * flog2(accl + 1e-12f)), d))) - droot;
            }
            o4[j0] = o;
        }
        if (hi_act) {
            float4 u = v1, o;
            if (use_sqrt) {
                acch = fmaf(w, u.x, p * acch);
                o.x = fsqrt(fmaf(u.x, fexp2(na * flog2(acch + 1e-12f)), d)) - droot;
                acch = fmaf(w, u.y, p * acch);
                o.y = fsqrt(fmaf(u.y, fexp2(na * flog2(acch + 1e-12f)), d)) - droot;
                acch = fmaf(w, u.z, p * acch);
                o.z = fsqrt(fmaf(u.z, fexp2(na * flog2(acch + 1e-12f)), d)) - droot;
                acch = fmaf(w, u.w, p * acch);
                o.w = fsqrt(fmaf(u.w, fexp2(na * flog2(acch + 1e-12f)), d)) - droot;
            } else {
                acch = fmaf(w, u.x, p * acch);
                o.x = fexp2(inv_r * flog2(fmaf(u.x, fexp2(na * flog2(acch + 1e-12f)), d))) - droot;
                acch = fmaf(w, u.y, p * acch);
                o.y = fexp2(inv_r * flog2(fmaf(u.y, fexp2(na * flog2(acch + 1e-12f)), d))) - droot;
                acch = fmaf(w, u.z, p * acch);
                o.z = fexp2(inv_r * flog2(fmaf(u.z, fexp2(na * flog2(acch + 1e-12f)), d))) - droot;
                acch = fmaf(w, u.w, p * acch);
                o.w = fexp2(inv_r * flog2(fmaf(u.w, fexp2(na * flog2(acch + 1e-12f)), d))) - droot;
            }
            o4[j1] = o;
        }

        v0 = n0;
        v1 = n1;
    }

    // output 1: x_length as float (harness reads whole d_out as f32)
    if (row == 0) {
        for (int i = tid; i < nlen; i += BLK)
            out[(size_t)rows * T_LEN + i] = (float)xlen[i];
    }
}

extern "C" void kernel_launch(void* const* d_in, const int* in_sizes, int n_in,
                              void* d_out, int out_size, void* d_ws, size_t ws_size,
                              hipStream_t stream) {
    const float* x     = (const float*)d_in[0];
    const float* alpha = (const float*)d_in[1];
    const float* delta = (const float*)d_in[2];
    const float* root  = (const float*)d_in[3];
    const float* emaw  = (const float*)d_in[4];
    const int*   xlen  = (const int*)d_in[5];
    float*       out   = (float*)d_out;

    const int C    = in_sizes[1];
    const int rows = in_sizes[0] / T_LEN;  // B*C
    const int nlen = in_sizes[5];

    hipLaunchKernelGGL(pcen_kernel, dim3(rows), dim3(BLK), 0, stream,
                       x, alpha, delta, root, emaw, xlen, out, C, rows, nlen);
}

// Round 8
// 54.047 us; speedup vs baseline: 1.3135x; 1.1974x over previous
//
#include <hip/hip_runtime.h>
#include <cmath>

// PCEN: out = (x / (FLOOR + ema(x,w))^a + d)^(1/r) - d^(1/r), plus x_length passthrough.
// One 256-thread block per (b,c) row of T=8000, processed as 4 tiles of 2048 elems.
// Each thread owns TWO dense float4s per tile (lo at tid, hi at tid+BLK) -> every
// load/store instruction is perfectly coalesced. EMA recurrence: per-segment affine
// transform + constant-multiplier Kogge-Stone wave scan (lo & hi interleaved), ONE
// LDS/barrier round per tile resolves both. NON-TEMPORAL output stores: out is
// never re-read, so keep it out of L2/L3 and leave the Infinity Cache to x
// (write-allocate was evicting x and doubling DRAM fetch traffic).
// Pointwise math: raw v_log_f32/v_exp_f32; root==2 fast path via v_sqrt_f32.

constexpr int T_LEN = 8000;
constexpr int T4    = T_LEN / 4;                   // 2000 float4 per row
constexpr int BLK   = 256;
constexpr int TILE4 = BLK * 2;                     // 512 float4 per tile
constexpr int NTILE = (T4 + TILE4 - 1) / TILE4;    // 4 tiles (last: hi partially active)

typedef float f32x4 __attribute__((ext_vector_type(4)));

__device__ __forceinline__ float fexp2(float x) { return __builtin_amdgcn_exp2f(x); }
__device__ __forceinline__ float flog2(float x) { return __builtin_amdgcn_logf(x); }
__device__ __forceinline__ float fsqrt(float x) { return __builtin_amdgcn_sqrtf(x); }

__device__ __forceinline__ void nt_store4(float* dst, float a, float b, float c, float d) {
    f32x4 v = { a, b, c, d };
    __builtin_nontemporal_store(v, reinterpret_cast<f32x4*>(dst));
}

__global__ __launch_bounds__(BLK, 8) void pcen_kernel(
    const float* __restrict__ x, const float* __restrict__ alpha,
    const float* __restrict__ delta, const float* __restrict__ root,
    const float* __restrict__ ema_w, const int* __restrict__ xlen,
    float* __restrict__ out, int C, int rows, int nlen)
{
    __shared__ float wLo[2][4], wHi[2][4];   // per-tile wave aggregates, parity dbuf

    const int tid  = threadIdx.x;
    const int lane = tid & 63;
    const int wid  = tid >> 6;
    const int row  = blockIdx.x;
    const int c    = row % C;

    const float w     = fminf(fmaxf(ema_w[c], 0.0f), 1.0f);
    const float p     = 1.0f - w;                 // EMA decay
    const float na    = -fminf(alpha[c], 1.0f);
    const float r     = fmaxf(root[c], 1.0f);
    const float inv_r = 1.0f / r;
    const float d     = delta[c];
    const bool  use_sqrt = (r == 2.0f);
    const float droot = use_sqrt ? fsqrt(d) : fexp2(inv_r * flog2(d));

    // scan constants by repeated squaring
    const float c1 = p * p * p * p;                           // p^4 (segment decay)
    const float c2 = c1 * c1, c3 = c2 * c2, c4 = c3 * c3,
                c5 = c4 * c4, c6 = c5 * c5;                   // p^8 .. p^128
    const float q  = c6 * c6;                                 // p^256 (wave span)
    const float q2 = q * q, q3 = q2 * q;                      // p^512, p^768
    const float ql = q2 * q2;                                 // p^1024 (half-tile span)
    // p^(4*lane); lane==0 select avoids 0*(-inf)=NaN when p==0
    const float lp  = flog2(p);
    const float p4l = (lane == 0) ? 1.0f : fexp2(4.0f * (float)lane * lp);
    const float qw  = (wid == 0) ? 1.0f : (wid == 1) ? q : (wid == 2) ? q2 : q3;

    const float4* x4   = reinterpret_cast<const float4*>(x + (size_t)row * T_LEN);
    float*        orow = out + (size_t)row * T_LEN;

    float carry = x[(size_t)row * T_LEN];          // jax scan init: acc = x[...,0]

    // tile 0 loads (lo always valid; hi valid for all full tiles)
    float4 v0 = x4[tid];
    float4 v1 = x4[tid + BLK];

    for (int t = 0; t < NTILE; ++t) {
        const int  j0     = t * TILE4 + tid;       // lo float4 index (always < T4)
        const int  j1     = j0 + BLK;              // hi float4 index
        const bool hi_act = (j1 < T4);
        const int  par    = t & 1;

        // ---- prefetch next tile (issued before the dependent scan chain) ----
        float4 n0 = make_float4(0.f, 0.f, 0.f, 0.f);
        float4 n1 = make_float4(0.f, 0.f, 0.f, 0.f);
        const int k0 = j0 + TILE4, k1 = j1 + TILE4;
        if (t + 1 < NTILE) {
            n0 = x4[k0];                           // lo of next tile always valid
            if (k1 < T4) n1 = x4[k1];
        }

        // ---- pass 1: per-segment transforms B = w * Horner over 4 elems ----
        float sl = v0.x;
        sl = fmaf(sl, p, v0.y); sl = fmaf(sl, p, v0.z); sl = fmaf(sl, p, v0.w);
        float bl = w * sl;
        float sh = v1.x;
        sh = fmaf(sh, p, v1.y); sh = fmaf(sh, p, v1.z); sh = fmaf(sh, p, v1.w);
        float bh = hi_act ? (w * sh) : 0.0f;

        // ---- Kogge-Stone inclusive scans (lo & hi interleaved), const mults ----
        float pl, ph;
        pl = __shfl_up(bl,  1, 64); ph = __shfl_up(bh,  1, 64);
        if (lane >=  1) { bl = fmaf(c1, pl, bl); bh = fmaf(c1, ph, bh); }
        pl = __shfl_up(bl,  2, 64); ph = __shfl_up(bh,  2, 64);
        if (lane >=  2) { bl = fmaf(c2, pl, bl); bh = fmaf(c2, ph, bh); }
        pl = __shfl_up(bl,  4, 64); ph = __shfl_up(bh,  4, 64);
        if (lane >=  4) { bl = fmaf(c3, pl, bl); bh = fmaf(c3, ph, bh); }
        pl = __shfl_up(bl,  8, 64); ph = __shfl_up(bh,  8, 64);
        if (lane >=  8) { bl = fmaf(c4, pl, bl); bh = fmaf(c4, ph, bh); }
        pl = __shfl_up(bl, 16, 64); ph = __shfl_up(bh, 16, 64);
        if (lane >= 16) { bl = fmaf(c5, pl, bl); bh = fmaf(c5, ph, bh); }
        pl = __shfl_up(bl, 32, 64); ph = __shfl_up(bh, 32, 64);
        if (lane >= 32) { bl = fmaf(c6, pl, bl); bh = fmaf(c6, ph, bh); }

        if (lane == 63) { wLo[par][wid] = bl; wHi[par][wid] = bh; }
        float ebl = __shfl_up(bl, 1, 64);
        float ebh = __shfl_up(bh, 1, 64);
        if (lane == 0) { ebl = 0.0f; ebh = 0.0f; }
        __syncthreads();

        // ---- compose wave prefixes + inter-tile carry (uniform per wave) ----
        const float L0 = wLo[par][0], L1 = wLo[par][1], L2 = wLo[par][2], L3 = wLo[par][3];
        const float H0 = wHi[par][0], H1 = wHi[par][1], H2 = wHi[par][2], H3 = wHi[par][3];
        float PL = 0.0f, PH = 0.0f;
        if (wid == 1)      { PL = L0;                        PH = H0; }
        else if (wid == 2) { PL = fmaf(q, L0, L1);           PH = fmaf(q, H0, H1); }
        else if (wid == 3) { PL = fmaf(q, fmaf(q, L0, L1), L2);
                             PH = fmaf(q, fmaf(q, H0, H1), H2); }
        const float TloB = fmaf(q, fmaf(q, fmaf(q, L0, L1), L2), L3);
        const float ThiB = fmaf(q, fmaf(q, fmaf(q, H0, H1), H2), H3);

        const float Elo = fmaf(qw, carry, PL);     // value entering this wave's lo span
        const float mid = fmaf(ql, carry, TloB);   // value after all lo (elem 1023)
        const float Ehi = fmaf(qw, mid, PH);       // value entering this wave's hi span
        carry = fmaf(ql, mid, ThiB);               // value after full tile

        float accl = fmaf(p4l, Elo, ebl);          // acc entering lane's lo segment
        float acch = fmaf(p4l, Ehi, ebh);          // acc entering lane's hi segment

        // ---- pass 2: exact EMA replay + pointwise PCEN, non-temporal stores ----
        {
            float4 u = v0;
            float ox, oy, oz, ow;
            if (use_sqrt) {
                accl = fmaf(w, u.x, p * accl);
                ox = fsqrt(fmaf(u.x, fexp2(na * flog2(accl + 1e-12f)), d)) - droot;
                accl = fmaf(w, u.y, p * accl);
                oy = fsqrt(fmaf(u.y, fexp2(na * flog2(accl + 1e-12f)), d)) - droot;
                accl = fmaf(w, u.z, p * accl);
                oz = fsqrt(fmaf(u.z, fexp2(na * flog2(accl + 1e-12f)), d)) - droot;
                accl = fmaf(w, u.w, p * accl);
                ow = fsqrt(fmaf(u.w, fexp2(na * flog2(accl + 1e-12f)), d)) - droot;
            } else {
                accl = fmaf(w, u.x, p * accl);
                ox = fexp2(inv_r * flog2(fmaf(u.x, fexp2(na * flog2(accl + 1e-12f)), d))) - droot;
                accl = fmaf(w, u.y, p * accl);
                oy = fexp2(inv_r * flog2(fmaf(u.y, fexp2(na * flog2(accl + 1e-12f)), d))) - droot;
                accl = fmaf(w, u.z, p * accl);
                oz = fexp2(inv_r * flog2(fmaf(u.z, fexp2(na * flog2(accl + 1e-12f)), d))) - droot;
                accl = fmaf(w, u.w, p * accl);
                ow = fexp2(inv_r * flog2(fmaf(u.w, fexp2(na * flog2(accl + 1e-12f)), d))) - droot;
            }
            nt_store4(orow + (size_t)j0 * 4, ox, oy, oz, ow);
        }
        if (hi_act) {
            float4 u = v1;
            float ox, oy, oz, ow;
            if (use_sqrt) {
                acch = fmaf(w, u.x, p * acch);
                ox = fsqrt(fmaf(u.x, fexp2(na * flog2(acch + 1e-12f)), d)) - droot;
                acch = fmaf(w, u.y, p * acch);
                oy = fsqrt(fmaf(u.y, fexp2(na * flog2(acch + 1e-12f)), d)) - droot;
                acch = fmaf(w, u.z, p * acch);
                oz = fsqrt(fmaf(u.z, fexp2(na * flog2(acch + 1e-12f)), d)) - droot;
                acch = fmaf(w, u.w, p * acch);
                ow = fsqrt(fmaf(u.w, fexp2(na * flog2(acch + 1e-12f)), d)) - droot;
            } else {
                acch = fmaf(w, u.x, p * acch);
                ox = fexp2(inv_r * flog2(fmaf(u.x, fexp2(na * flog2(acch + 1e-12f)), d))) - droot;
                acch = fmaf(w, u.y, p * acch);
                oy = fexp2(inv_r * flog2(fmaf(u.y, fexp2(na * flog2(acch + 1e-12f)), d))) - droot;
                acch = fmaf(w, u.z, p * acch);
                oz = fexp2(inv_r * flog2(fmaf(u.z, fexp2(na * flog2(acch + 1e-12f)), d))) - droot;
                acch = fmaf(w, u.w, p * acch);
                ow = fexp2(inv_r * flog2(fmaf(u.w, fexp2(na * flog2(acch + 1e-12f)), d))) - droot;
            }
            nt_store4(orow + (size_t)j1 * 4, ox, oy, oz, ow);
        }

        v0 = n0;
        v1 = n1;
    }

    // output 1: x_length as float (harness reads whole d_out as f32)
    if (row == 0) {
        for (int i = tid; i < nlen; i += BLK)
            out[(size_t)rows * T_LEN + i] = (float)xlen[i];
    }
}

extern "C" void kernel_launch(void* const* d_in, const int* in_sizes, int n_in,
                              void* d_out, int out_size, void* d_ws, size_t ws_size,
                              hipStream_t stream) {
    const float* x     = (const float*)d_in[0];
    const float* alpha = (const float*)d_in[1];
    const float* delta = (const float*)d_in[2];
    const float* root  = (const float*)d_in[3];
    const float* emaw  = (const float*)d_in[4];
    const int*   xlen  = (const int*)d_in[5];
    float*       out   = (float*)d_out;

    const int C    = in_sizes[1];
    const int rows = in_sizes[0] / T_LEN;  // B*C
    const int nlen = in_sizes[5];

    hipLaunchKernelGGL(pcen_kernel, dim3(rows), dim3(BLK), 0, stream,
                       x, alpha, delta, root, emaw, xlen, out, C, rows, nlen);
}